// Round 8
// baseline (544.694 us; speedup 1.0000x reference)
//
#include <hip/hip_runtime.h>
#include <cmath>

// x [B=4096][T=512][D=4], H=32, gates 4H=128 (PyTorch order i,f,g,o).
constexpr int T   = 512;
constexpr int D   = 4;
constexpr int H   = 32;
constexpr int BT  = 8;     // batch per block (MFMA N half-used; buys 2 blocks/CU)
constexpr int BLK = 512;   // 8 waves: wave w owns M-tile w (rows 16w..16w+15) of BOTH layers

typedef short bf8 __attribute__((ext_vector_type(8)));  // 8 bf16 (4 VGPRs)
typedef float f4  __attribute__((ext_vector_type(4)));  // MFMA C/D

static __device__ __forceinline__ float sigm(float z) {
    return __builtin_amdgcn_rcpf(1.0f + __expf(-z));
}
static __device__ __forceinline__ float tanh_f(float z) {
    return fmaf(__builtin_amdgcn_rcpf(1.0f + __expf(-2.0f * z)), 2.0f, -1.0f);
}
// fp32 -> bf16 hi (truncate) + bf16 lo (residual): hi+lo ~ 16 mantissa bits
static __device__ __forceinline__ void splitf(float v, short& hi, short& lo) {
    unsigned uv = __float_as_uint(v);
    hi = (short)(uv >> 16);
    float r = v - __uint_as_float(uv & 0xffff0000u);
    lo = (short)(__float_as_uint(r) >> 16);
}

// Grid 512 x 512 threads = 2 blocks/CU, 4 waves/SIMD.
// Phase A (all 8 waves): wave w computes M-tile w of L1 step i (3 MFMAs,
//   C preloaded from xg = bias0 + W_ih0 x(i), exact fp32) and M-tile w of
//   L2 step i-1 (2 independent 3-chains + add). h products use split-bf16
//   (hi*hi + hi*lo + lo*hi).
// Phase B (512 threads, 1 unit each): thread (layer, u, n) reads 4 raw
//   gates, does the 10-transcendental state update, writes h pre-split;
//   every thread also computes 2 rows of xg(i+1) via scalar dot-4.
// 2 barriers/step; xg/g/h buffer roles never overlap within a phase.
__global__ __launch_bounds__(BLK, 4) void lstm_mfma512(
    const float* __restrict__ x,
    const float* __restrict__ W_ih0, const float* __restrict__ W_hh0,
    const float* __restrict__ b_ih0, const float* __restrict__ b_hh0,
    const float* __restrict__ W_ih1, const float* __restrict__ W_hh1,
    const float* __restrict__ b_ih1, const float* __restrict__ b_hh1,
    const float* __restrict__ W_out, const float* __restrict__ b_out,
    float* __restrict__ out)
{
    __shared__ __align__(16) float xg[16][132];     // bias0 + W_ih0 x(t)  [batchcol][row]
    __shared__ __align__(16) float g0[16][132];     // raw L1 gates
    __shared__ __align__(16) float g1[16][132];     // raw L2 gates
    __shared__ __align__(16) short h0hi[16][56];    // h0 split-bf16 (cols 8-15 unused)
    __shared__ __align__(16) short h0lo[16][56];
    __shared__ __align__(16) short h1hi[16][56];
    __shared__ __align__(16) short h1lo[16][56];
    __shared__ __align__(16) float h1f[BT][36];     // final h1 fp32 for the head

    const int tid  = threadIdx.x;
    const int w    = tid >> 6;        // wave id = M-tile id (0..7)
    const int lane = tid & 63;
    const int q    = lane >> 4;       // quad
    const int nl   = lane & 15;       // MFMA batch col
    const int b0   = blockIdx.x * BT;

    // zero h LDS
    for (int idx = tid; idx < 16 * 56; idx += BLK) {
        (&h0hi[0][0])[idx] = 0; (&h0lo[0][0])[idx] = 0;
        (&h1hi[0][0])[idx] = 0; (&h1lo[0][0])[idx] = 0;
    }

    // ---- A-frag weights for tile w: lane holds row 16w+nl, k = 8q+j ----
    bf8 whh0h, whh0l, wih1h, wih1l, whh1h, whh1l;
    f4  bias1;
    {
        const int row = 16 * w + nl;
        #pragma unroll
        for (int j = 0; j < 8; ++j) {
            short a, b;
            splitf(W_hh0[row * H + 8 * q + j], a, b); whh0h[j] = a; whh0l[j] = b;
            splitf(W_ih1[row * H + 8 * q + j], a, b); wih1h[j] = a; wih1l[j] = b;
            splitf(W_hh1[row * H + 8 * q + j], a, b); whh1h[j] = a; whh1l[j] = b;
        }
        #pragma unroll
        for (int r = 0; r < 4; ++r) {
            const int gr = 16 * w + 4 * q + r;
            bias1[r] = b_ih1[gr] + b_hh1[gr];
        }
    }

    // ---- xg-duty: thread computes gate rows rx, rx+64 for batch col nx ----
    const int rx = tid >> 3;          // 0..63
    const int nx = tid & 7;
    float wxa[4], wxb[4];
    #pragma unroll
    for (int d = 0; d < 4; ++d) {
        wxa[d] = W_ih0[rx * D + d];
        wxb[d] = W_ih0[(rx + 64) * D + d];
    }
    const float bx0 = b_ih0[rx] + b_hh0[rx];
    const float bx1 = b_ih0[rx + 64] + b_hh0[rx + 64];
    const float* xrow = x + (size_t)(b0 + nx) * (T * D);

    // ---- phase-B mapping: 1 (layer, unit, batch) per thread ----
    const int layer = tid >> 8;       // 0: L1, 1: L2
    const int sub   = tid & 255;
    const int u     = sub >> 3;       // unit 0..31
    const int n     = sub & 7;        // batch 0..7
    float c = 0.0f;                   // cell state of the owned unit

    // xg(0)
    {
        float4 xv = *(const float4*)xrow;
        xg[nx][rx]      = fmaf(wxa[3], xv.w, fmaf(wxa[2], xv.z, fmaf(wxa[1], xv.y, fmaf(wxa[0], xv.x, bx0))));
        xg[nx][rx + 64] = fmaf(wxb[3], xv.w, fmaf(wxb[2], xv.z, fmaf(wxb[1], xv.y, fmaf(wxb[0], xv.x, bx1))));
    }
    __syncthreads();

    #pragma unroll 1
    for (int i = 0; i <= T; ++i) {
        // ================= phase A: MFMA raw gates =================
        bf8 h0h = *(const bf8*)&h0hi[nl][8 * q];    // h0(i-1)
        bf8 h0l = *(const bf8*)&h0lo[nl][8 * q];
        bf8 h1h = *(const bf8*)&h1hi[nl][8 * q];    // h1(i-2)
        bf8 h1l = *(const bf8*)&h1lo[nl][8 * q];

        f4 a = *(const f4*)&xg[nl][16 * w + 4 * q]; // bias0 + x-gate (exact)
        a = __builtin_amdgcn_mfma_f32_16x16x32_bf16(whh0h, h0h, a, 0, 0, 0);
        a = __builtin_amdgcn_mfma_f32_16x16x32_bf16(whh0h, h0l, a, 0, 0, 0);
        a = __builtin_amdgcn_mfma_f32_16x16x32_bf16(whh0l, h0h, a, 0, 0, 0);
        *(f4*)&g0[nl][16 * w + 4 * q] = a;

        f4 p = bias1;                               // two independent 3-chains
        p = __builtin_amdgcn_mfma_f32_16x16x32_bf16(wih1h, h0h, p, 0, 0, 0);
        p = __builtin_amdgcn_mfma_f32_16x16x32_bf16(wih1h, h0l, p, 0, 0, 0);
        p = __builtin_amdgcn_mfma_f32_16x16x32_bf16(wih1l, h0h, p, 0, 0, 0);
        f4 r2 = {0.0f, 0.0f, 0.0f, 0.0f};
        r2 = __builtin_amdgcn_mfma_f32_16x16x32_bf16(whh1h, h1h, r2, 0, 0, 0);
        r2 = __builtin_amdgcn_mfma_f32_16x16x32_bf16(whh1h, h1l, r2, 0, 0, 0);
        r2 = __builtin_amdgcn_mfma_f32_16x16x32_bf16(whh1l, h1h, r2, 0, 0, 0);
        f4 gsum = p + r2;
        *(f4*)&g1[nl][16 * w + 4 * q] = gsum;
        __syncthreads();

        // ================= phase B =================
        // xg for t = i+1 (issue the global load early; compute after update)
        const int tn = (i + 1 < T) ? (i + 1) : (T - 1);
        float4 xv = *(const float4*)(xrow + tn * D);

        const bool act = (layer == 0) ? (i < T) : (i >= 1);
        if (act) {
            const float (*gb)[132] = layer ? g1 : g0;
            float gi_ = gb[n][u];
            float gf_ = gb[n][32 + u];
            float gg_ = gb[n][64 + u];
            float go_ = gb[n][96 + u];
            float iv = sigm(gi_), fv = sigm(gf_);
            float gv = tanh_f(gg_), ov = sigm(go_);
            c = fmaf(fv, c, iv * gv);
            float hv = ov * tanh_f(c);
            short ha, hb; splitf(hv, ha, hb);
            if (layer == 0) {
                h0hi[n][u] = ha; h0lo[n][u] = hb;
            } else {
                h1hi[n][u] = ha; h1lo[n][u] = hb;
                if (i == T) h1f[n][u] = hv;         // h1(T-1) for the head
            }
        }
        xg[nx][rx]      = fmaf(wxa[3], xv.w, fmaf(wxa[2], xv.z, fmaf(wxa[1], xv.y, fmaf(wxa[0], xv.x, bx0))));
        xg[nx][rx + 64] = fmaf(wxb[3], xv.w, fmaf(wxb[2], xv.z, fmaf(wxb[1], xv.y, fmaf(wxb[0], xv.x, bx1))));
        __syncthreads();
    }

    // ---- output head: out[b0+n] = b_out + W_out . h1(T-1) ----
    if (tid < BT) {
        float acc = b_out[0];
        #pragma unroll
        for (int uu = 0; uu < H; ++uu) acc = fmaf(W_out[uu], h1f[tid][uu], acc);
        out[b0 + tid] = acc;
    }
}

extern "C" void kernel_launch(void* const* d_in, const int* in_sizes, int n_in,
                              void* d_out, int out_size, void* d_ws, size_t ws_size,
                              hipStream_t stream) {
    const float* x     = (const float*)d_in[0];
    const float* W_ih0 = (const float*)d_in[1];
    const float* W_hh0 = (const float*)d_in[2];
    const float* b_ih0 = (const float*)d_in[3];
    const float* b_hh0 = (const float*)d_in[4];
    const float* W_ih1 = (const float*)d_in[5];
    const float* W_hh1 = (const float*)d_in[6];
    const float* b_ih1 = (const float*)d_in[7];
    const float* b_hh1 = (const float*)d_in[8];
    const float* W_out = (const float*)d_in[9];
    const float* b_out = (const float*)d_in[10];
    float* out = (float*)d_out;

    const int B = out_size;          // 4096
    lstm_mfma512<<<B / BT, BLK, 0, stream>>>(x, W_ih0, W_hh0, b_ih0, b_hh0,
                                             W_ih1, W_hh1, b_ih1, b_hh1,
                                             W_out, b_out, out);
}